// Round 2
// baseline (1663.927 us; speedup 1.0000x reference)
//
#include <hip/hip_runtime.h>

// Vector quantization: z [32768,256] f32, codebook [8192,256] f32
// outputs: z_q [32768,256] f32, indices [32768] (as float)
//
// Strategy: bitwise-replicate the float32 numpy reference:
//   d_k = fl32( fl32( Z_row - fl32(2*dot_k) ) + C_k ),  argmin, first-index ties.
// Z_row / C_k replicate np.sum pairwise summation exactly; dot error (~1e-9)
// is 4 orders of magnitude below the f32 bucket (ulp(256) ~ 3e-5), harmless.

#define NROWS 32768
#define DIM   256
#define KCB   8192

// scratch inside z_q region of d_out (gather overwrites it last)
#define OFF_PM1 0        // [2][32768] per-split min
#define OFF_PI1 65536    // [2][32768] per-split idx (as float)
#define OFF_ZSQ 131072   // [32768] Z (np-pairwise f32)
#define OFF_CSQ 163840   // [8192]  C (np-pairwise f32)
#define OFF_IDX 8388608  // final indices (float), real output tail

// numpy pairwise sum of squares, n=256 contiguous, bitwise-faithful:
// 256 -> 128+128; each 128-block: 8 accumulators stride-8;
// combine ((r0+r1)+(r2+r3))+((r4+r5)+(r6+r7)); total = blk0+blk1.
__device__ float np_sumsq_256(const float* __restrict__ p) {
#pragma clang fp contract(off)
    float blk[2];
    #pragma unroll
    for (int b = 0; b < 2; ++b) {
        const float* q = p + b * 128;
        float r[8];
        #pragma unroll
        for (int j = 0; j < 8; ++j) r[j] = __fmul_rn(q[j], q[j]);
        for (int i = 8; i < 128; i += 8) {
            #pragma unroll
            for (int j = 0; j < 8; ++j)
                r[j] = __fadd_rn(r[j], __fmul_rn(q[i + j], q[i + j]));
        }
        blk[b] = __fadd_rn(
            __fadd_rn(__fadd_rn(r[0], r[1]), __fadd_rn(r[2], r[3])),
            __fadd_rn(__fadd_rn(r[4], r[5]), __fadd_rn(r[6], r[7])));
    }
    return __fadd_rn(blk[0], blk[1]);
}

__global__ void vq_sumsq_kernel(const float* __restrict__ a,
                                float* __restrict__ out, int nrows) {
    int r = blockIdx.x * blockDim.x + threadIdx.x;
    if (r < nrows) out[r] = np_sumsq_256(a + (size_t)r * DIM);
}

// Fused distance GEMM + per-row argmin with faithful f32 rounding + tie-break.
// Grid (256 row-blocks, 2 k-splits), 512 threads = 16 row-thr x 32 code-thr.
// Per thread: 8 rows x 4 codes.
__global__ __launch_bounds__(512, 4) void vq_passA_kernel(
    const float* __restrict__ z, const float* __restrict__ cb,
    const float* __restrict__ csq32, const float* __restrict__ zsq32,
    float* __restrict__ pm1, float* __restrict__ pi1) {
    __shared__ float zT[32][132];
    __shared__ float eT[32][132];
    const int tid = threadIdx.x;
    const int tx = tid & 31;    // code-thread
    const int ty = tid >> 5;    // row-thread
    const int row0 = blockIdx.x * 128;
    const int cbase = blockIdx.y * 4096;

    float Zr[8];
    #pragma unroll
    for (int r = 0; r < 8; ++r) Zr[r] = zsq32[row0 + ty * 8 + r];

    float m1[8]; int i1[8];
    #pragma unroll
    for (int r = 0; r < 8; ++r) { m1[r] = 3.4e38f; i1[r] = 0; }

    for (int cblk = 0; cblk < 32; ++cblk) {
        const int c0 = cbase + cblk * 128;
        float acc[8][4];
        #pragma unroll
        for (int r = 0; r < 8; ++r)
            #pragma unroll
            for (int j = 0; j < 4; ++j) acc[r][j] = 0.0f;

        for (int dch = 0; dch < 8; ++dch) {
            const int d0 = dch * 32;
            __syncthreads();   // previous tile fully consumed
            #pragma unroll
            for (int p = 0; p < 2; ++p) {
                int f = tid + p * 512;          // 0..1023
                int rr = f >> 3, dg = f & 7;
                float4 v = *reinterpret_cast<const float4*>(
                    &z[(size_t)(row0 + rr) * DIM + d0 + dg * 4]);
                zT[dg * 4 + 0][rr] = v.x; zT[dg * 4 + 1][rr] = v.y;
                zT[dg * 4 + 2][rr] = v.z; zT[dg * 4 + 3][rr] = v.w;
                float4 e = *reinterpret_cast<const float4*>(
                    &cb[(size_t)(c0 + rr) * DIM + d0 + dg * 4]);
                eT[dg * 4 + 0][rr] = e.x; eT[dg * 4 + 1][rr] = e.y;
                eT[dg * 4 + 2][rr] = e.z; eT[dg * 4 + 3][rr] = e.w;
            }
            __syncthreads();
            #pragma unroll
            for (int d = 0; d < 32; ++d) {
                float4 za = *reinterpret_cast<const float4*>(&zT[d][ty * 8]);
                float4 zb = *reinterpret_cast<const float4*>(&zT[d][ty * 8 + 4]);
                float4 e4 = *reinterpret_cast<const float4*>(&eT[d][tx * 4]);
                float zr[8] = {za.x, za.y, za.z, za.w, zb.x, zb.y, zb.z, zb.w};
                float ec[4] = {e4.x, e4.y, e4.z, e4.w};
                #pragma unroll
                for (int r = 0; r < 8; ++r)
                    #pragma unroll
                    for (int j = 0; j < 4; ++j)
                        acc[r][j] = fmaf(zr[r], ec[j], acc[r][j]);
            }
        }
        // epilogue: d = fl(fl(Z - 2*dot) + C), running argmin (c ascending ->
        // strict < keeps lowest index on exact ties)
        #pragma unroll
        for (int j = 0; j < 4; ++j) {
            int c = c0 + tx * 4 + j;
            float cs = csq32[c];
            #pragma unroll
            for (int r = 0; r < 8; ++r) {
                float t = __fsub_rn(Zr[r], __fmul_rn(2.0f, acc[r][j]));
                float s = __fadd_rn(t, cs);
                if (s < m1[r]) { m1[r] = s; i1[r] = c; }
            }
        }
    }

    // reduce argmin across the 32 code-threads with first-index tie-break
    #pragma unroll
    for (int st = 16; st >= 1; st >>= 1) {
        #pragma unroll
        for (int r = 0; r < 8; ++r) {
            float o1 = __shfl_xor(m1[r], st);
            int   oi = __shfl_xor(i1[r], st);
            if (o1 < m1[r] || (o1 == m1[r] && oi < i1[r])) { m1[r] = o1; i1[r] = oi; }
        }
    }
    if (tx == 0) {
        #pragma unroll
        for (int r = 0; r < 8; ++r) {
            int row = row0 + ty * 8 + r;
            int o = blockIdx.y * NROWS + row;
            pm1[o] = m1[r];
            pi1[o] = (float)i1[r];
        }
    }
}

__global__ void vq_merge_kernel(const float* __restrict__ pm1,
                                const float* __restrict__ pi1,
                                float* __restrict__ outIdx) {
    int n = blockIdx.x * blockDim.x + threadIdx.x;
    float a1 = pm1[n];         int ai = (int)pi1[n];           // codes 0..4095
    float b1 = pm1[NROWS + n]; int bi = (int)pi1[NROWS + n];   // codes 4096..8191
    // tie -> split 0 (lower indices) wins, matching np.argmin first-occurrence
    int idx = (b1 < a1) ? bi : ai;
    outIdx[n] = (float)idx;
}

__global__ void vq_gather_kernel(const float* __restrict__ cb,
                                 const float* __restrict__ idxF,
                                 float4* __restrict__ out4) {
    int g = blockIdx.x * blockDim.x + threadIdx.x;
    const float4* cb4 = reinterpret_cast<const float4*>(cb);
    for (int i = g; i < NROWS * 64; i += gridDim.x * blockDim.x) {
        int row = i >> 6, q = i & 63;
        int idx = (int)idxF[row];
        out4[i] = cb4[(size_t)idx * 64 + q];
    }
}

extern "C" void kernel_launch(void* const* d_in, const int* in_sizes, int n_in,
                              void* d_out, int out_size, void* d_ws, size_t ws_size,
                              hipStream_t stream) {
    const float* z  = (const float*)d_in[0];
    const float* cb = (const float*)d_in[1];
    float* out = (float*)d_out;

    float* pm1   = out + OFF_PM1;
    float* pi1   = out + OFF_PI1;
    float* zsq32 = out + OFF_ZSQ;
    float* csq32 = out + OFF_CSQ;
    float* idxF  = out + OFF_IDX;

    vq_sumsq_kernel<<<KCB / 256, 256, 0, stream>>>(cb, csq32, KCB);
    vq_sumsq_kernel<<<NROWS / 256, 256, 0, stream>>>(z, zsq32, NROWS);
    vq_passA_kernel<<<dim3(NROWS / 128, 2), 512, 0, stream>>>(z, cb, csq32, zsq32, pm1, pi1);
    vq_merge_kernel<<<NROWS / 256, 256, 0, stream>>>(pm1, pi1, idxF);
    vq_gather_kernel<<<2048, 256, 0, stream>>>(cb, idxF, (float4*)out);
}